// Round 1
// baseline (173.986 us; speedup 1.0000x reference)
//
#include <hip/hip_runtime.h>

// Loss_8615704396494: masked L1 + 0.1 * bone-direction MSE over [B=128,T=1024,150] fp32.
// Memory-bound (157.3 MB read, scalar out).
//
// R6: de-lockstep. R5's two __syncthreads per iteration each drain vmcnt(0)
// (HIP lowers __syncthreads to s_waitcnt vmcnt(0) lgkmcnt(0) + s_barrier), so the
// register prefetch only overlapped the ~750-cycle compute phase and memory service
// was exposed serially each iteration (VALUBusy 17%, HBM 16%, occupancy 30% ->
// latency-bound bursts, 2.5 TB/s effective).
// Now each WAVE owns a private 9.6 KB LDS slice (8 rows x 150 f x 2 arrays):
// stage own span -> compute -> prefetch next span, NO barriers in the main loop.
// Same-wave LDS ops are in-order and every ds_read is consumed before the next
// iteration's ds_writes, so the private-slice WAR is safe without sync.
// 16 independent waves/CU x 10 outstanding float4 each = continuous memory issue.
// L1 term computed elementwise straight from the staged registers (tail guarded);
// the LDS pass only does the bone MSE.

#define ROW_F    150
#define ROWS_PW  8                    // rows per wave-span
#define SPAN_F   (ROWS_PW * ROW_F)    // 1200 floats per array per wave-span
#define SPAN_F4  (SPAN_F / 4)         // 300 float4
#define WAVES_PB 4
#define GRID     1024
#define TOTAL_WAVES (GRID * WAVES_PB) // 4096 waves; 16384 spans -> iters = 4

__global__ __launch_bounds__(256, 4) void loss_kernel(
    const float* __restrict__ preds,
    const float* __restrict__ targets,
    float* __restrict__ out,
    int iters, float inv_count)
{
    const float EPS = 1e-8f;
    __shared__ float sp[WAVES_PB][SPAN_F];
    __shared__ float st[WAVES_PB][SPAN_F];
    __shared__ float wsum[WAVES_PB];

    const int tid  = threadIdx.x;
    const int lane = tid & 63;
    const int wid  = tid >> 6;

    const float4* gp4 = reinterpret_cast<const float4*>(preds);
    const float4* gt4 = reinterpret_cast<const float4*>(targets);
    float4* sp4 = reinterpret_cast<float4*>(sp[wid]);
    float4* st4 = reinterpret_cast<float4*>(st[wid]);

    // Per-lane float4 slots within the wave's 300-float4 span: 4 full + 1 tail.
    const int g0 = lane, g1 = lane + 64, g2 = lane + 128, g3 = lane + 192, g4 = lane + 256;
    const bool w4 = (g4 < SPAN_F4);          // lane < 44
    const int g4c = w4 ? g4 : (SPAN_F4 - 1); // clamped (uniform flow, stays in VGPRs)

    // Compute mapping inside the wave: 8 rows x 8 segments.
    const int row = lane >> 3;               // 0..7
    const int seg = lane & 7;                // 0..7
    const int j0 = (seg < 2) ? seg * 7 : 14 + (seg - 2) * 6;  // segs 0,1: 7 bones; else 6
    const int j1 = (seg < 2) ? j0 + 7 : j0 + 6;

    float l1 = 0.0f, mse = 0.0f;

    const int wglobal = blockIdx.x * WAVES_PB + wid;

    // Prologue prefetch: span = wglobal
    size_t sb = (size_t)wglobal * SPAN_F4;
    float4 rp0 = gp4[sb + g0], rp1 = gp4[sb + g1], rp2 = gp4[sb + g2],
           rp3 = gp4[sb + g3], rp4 = gp4[sb + g4c];
    float4 rt0 = gt4[sb + g0], rt1 = gt4[sb + g1], rt2 = gt4[sb + g2],
           rt3 = gt4[sb + g3], rt4 = gt4[sb + g4c];

#define L1ACC(P, T) do {                                         \
        l1 += ((T).x != 0.0f) ? fabsf((P).x - (T).x) : 0.0f;     \
        l1 += ((T).y != 0.0f) ? fabsf((P).y - (T).y) : 0.0f;     \
        l1 += ((T).z != 0.0f) ? fabsf((P).z - (T).z) : 0.0f;     \
        l1 += ((T).w != 0.0f) ? fabsf((P).w - (T).w) : 0.0f;     \
    } while (0)

    for (int it = 0; it < iters; ++it) {
        // regs -> private LDS slice (compiler inserts counted vmcnt waits here)
        sp4[g0] = rp0; st4[g0] = rt0;
        sp4[g1] = rp1; st4[g1] = rt1;
        sp4[g2] = rp2; st4[g2] = rt2;
        sp4[g3] = rp3; st4[g3] = rt3;
        if (w4) { sp4[g4] = rp4; st4[g4] = rt4; }

        // L1 term directly from the registers (must precede the prefetch overwrite).
        L1ACC(rp0, rt0); L1ACC(rp1, rt1); L1ACC(rp2, rt2); L1ACC(rp3, rt3);
        if (w4) L1ACC(rp4, rt4);

        // Issue next span's loads; in flight during the bone compute below.
        if (it + 1 < iters) {
            size_t nb = (size_t)(wglobal + (size_t)(it + 1) * TOTAL_WAVES) * SPAN_F4;
            rp0 = gp4[nb + g0]; rp1 = gp4[nb + g1]; rp2 = gp4[nb + g2];
            rp3 = gp4[nb + g3]; rp4 = gp4[nb + g4c];
            rt0 = gt4[nb + g0]; rt1 = gt4[nb + g1]; rt2 = gt4[nb + g2];
            rt3 = gt4[nb + g3]; rt4 = gt4[nb + g4c];
        }

        // ---- Bone-direction MSE from the private LDS slice ----
        const float* rpb = &sp[wid][row * ROW_F];
        const float* rtb = &st[wid][row * ROW_F];

        float pmP[3], tmP[3];
#pragma unroll
        for (int c = 0; c < 3; ++c) {
            float t = rtb[3 * j0 + c];
            float p = rpb[3 * j0 + c];
            pmP[c] = (t != 0.0f) ? p : 0.0f;   // masked pred
            tmP[c] = t;                        // masked target == target
        }

        for (int b = j0; b < j1; ++b) {
            int jn = b + 1;
            if (jn == 50) jn = 0;              // wrap bone (seg 7), wave-uniform
            float pmN[3], tmN[3];
#pragma unroll
            for (int c = 0; c < 3; ++c) {
                float t = rtb[3 * jn + c];
                float p = rpb[3 * jn + c];
                pmN[c] = (t != 0.0f) ? p : 0.0f;
                tmN[c] = t;
            }
            float dp[3], dt[3], lp = 0.0f, lt = 0.0f;
#pragma unroll
            for (int c = 0; c < 3; ++c) {
                dp[c] = pmP[c] - pmN[c];
                dt[c] = tmP[c] - tmN[c];
                lp += dp[c] * dp[c];
                lt += dt[c] * dt[c];
            }
            float ip = __builtin_amdgcn_rcpf(__builtin_amdgcn_sqrtf(lp) + EPS);
            float iq = __builtin_amdgcn_rcpf(__builtin_amdgcn_sqrtf(lt) + EPS);
#pragma unroll
            for (int c = 0; c < 3; ++c) {
                float d = dp[c] * ip - dt[c] * iq;
                d = (tmP[c] != 0.0f) ? d : 0.0f;   // source-joint mask
                mse += d * d;
            }
#pragma unroll
            for (int c = 0; c < 3; ++c) { pmP[c] = pmN[c]; tmP[c] = tmN[c]; }
        }
    }

    // ---- Reduce: loss = (l1 + 0.1*mse) / COUNT ----
    float part = (l1 + 0.1f * mse) * inv_count;
#pragma unroll
    for (int off = 32; off > 0; off >>= 1)
        part += __shfl_down(part, off, 64);

    if (lane == 0) wsum[wid] = part;
    __syncthreads();                        // only barrier in the kernel
    if (tid == 0) {
        atomicAdd(out, wsum[0] + wsum[1] + wsum[2] + wsum[3]);
    }
}

extern "C" void kernel_launch(void* const* d_in, const int* in_sizes, int n_in,
                              void* d_out, int out_size, void* d_ws, size_t ws_size,
                              hipStream_t stream)
{
    const float* preds   = (const float*)d_in[0];
    const float* targets = (const float*)d_in[1];
    float* out = (float*)d_out;

    // d_out is re-poisoned to 0xAA before every timed launch — zero it (capture-safe).
    hipMemsetAsync(out, 0, sizeof(float) * out_size, stream);

    int n_elems = in_sizes[0];              // 128*1024*150 = 19,660,800
    int n_rows  = n_elems / ROW_F;          // 131072
    int spans   = n_rows / ROWS_PW;         // 16384
    float inv_count = 1.0f / (float)n_elems;

    int iters = spans / TOTAL_WAVES;        // 4
    loss_kernel<<<GRID, 256, 0, stream>>>(preds, targets, out, iters, inv_count);
}